// Round 1
// baseline (260.806 us; speedup 1.0000x reference)
//
#include <hip/hip_runtime.h>
#include <hip/hip_bf16.h>

// Problem dims (fixed by setup_inputs): b=8, t=64, s=512, qu=vu=d=512.
#define B_  8
#define T_  64
#define S_  512
#define D_  512

#define TLOG2E 2.8853900817779268f   // 2*log2(e)
#define LOG2E  1.4426950408889634f

__device__ __forceinline__ float tanh_fast(float x) {
    // tanh(x) = 1 - 2/(exp(2x)+1); v_exp_f32 + v_rcp_f32, ~1 ulp each.
    float e2 = __builtin_amdgcn_exp2f(x * TLOG2E);
    float r  = __builtin_amdgcn_rcpf(e2 + 1.0f);
    return fmaf(-2.0f, r, 1.0f);   // handles e2=inf -> r=0 -> 1; e2=0 -> r=1 -> -1
}

// ---------------------------------------------------------------------------
// f32 tiled GEMM: C[M,N] = A[M,K] * B[K,N] + bias[N]
// BM=BN=64, BK=16, 256 threads, 4x4 microtile per thread.
// ---------------------------------------------------------------------------
#define BM 64
#define BN 64
#define BK 16

__global__ __launch_bounds__(256) void gemm_bias(
    const float* __restrict__ A, const float* __restrict__ B,
    const float* __restrict__ bias, float* __restrict__ C,
    int M, int N, int K)
{
    __shared__ float As[BK][BM + 4];   // +4 pad: keeps 16B alignment, breaks bank aliasing
    __shared__ float Bs[BK][BN + 4];

    const int tid = threadIdx.x;
    const int bx = blockIdx.x, by = blockIdx.y;
    const int tx = tid & 15, ty = tid >> 4;

    float acc[4][4] = {};

    const int a_row = tid >> 2;          // 0..63
    const int a_k4  = (tid & 3) * 4;     // 0,4,8,12
    const int b_k   = tid >> 4;          // 0..15
    const int b_c4  = (tid & 15) * 4;    // 0..60

    const float* Ablk = A + (size_t)(by * BM) * K;
    const float* Bblk = B + bx * BN;

    for (int k0 = 0; k0 < K; k0 += BK) {
        float4 av = *(const float4*)(Ablk + (size_t)a_row * K + k0 + a_k4);
        float4 bv = *(const float4*)(Bblk + (size_t)(k0 + b_k) * N + b_c4);
        As[a_k4 + 0][a_row] = av.x;
        As[a_k4 + 1][a_row] = av.y;
        As[a_k4 + 2][a_row] = av.z;
        As[a_k4 + 3][a_row] = av.w;
        *(float4*)&Bs[b_k][b_c4] = bv;
        __syncthreads();
#pragma unroll
        for (int kk = 0; kk < BK; ++kk) {
            float4 a = *(const float4*)&As[kk][ty * 4];
            float4 b = *(const float4*)&Bs[kk][tx * 4];
            acc[0][0] = fmaf(a.x, b.x, acc[0][0]);
            acc[0][1] = fmaf(a.x, b.y, acc[0][1]);
            acc[0][2] = fmaf(a.x, b.z, acc[0][2]);
            acc[0][3] = fmaf(a.x, b.w, acc[0][3]);
            acc[1][0] = fmaf(a.y, b.x, acc[1][0]);
            acc[1][1] = fmaf(a.y, b.y, acc[1][1]);
            acc[1][2] = fmaf(a.y, b.z, acc[1][2]);
            acc[1][3] = fmaf(a.y, b.w, acc[1][3]);
            acc[2][0] = fmaf(a.z, b.x, acc[2][0]);
            acc[2][1] = fmaf(a.z, b.y, acc[2][1]);
            acc[2][2] = fmaf(a.z, b.z, acc[2][2]);
            acc[2][3] = fmaf(a.z, b.w, acc[2][3]);
            acc[3][0] = fmaf(a.w, b.x, acc[3][0]);
            acc[3][1] = fmaf(a.w, b.y, acc[3][1]);
            acc[3][2] = fmaf(a.w, b.z, acc[3][2]);
            acc[3][3] = fmaf(a.w, b.w, acc[3][3]);
        }
        __syncthreads();
    }

    const int row0 = by * BM + ty * 4;
    const int col0 = bx * BN + tx * 4;
    float4 bi = *(const float4*)(bias + col0);
#pragma unroll
    for (int i = 0; i < 4; ++i) {
        float4 o;
        o.x = acc[i][0] + bi.x;
        o.y = acc[i][1] + bi.y;
        o.z = acc[i][2] + bi.z;
        o.w = acc[i][3] + bi.w;
        *(float4*)(C + (size_t)(row0 + i) * N + col0) = o;
    }
}

// ---------------------------------------------------------------------------
// Fused scores + softmax + context. One block per (b,t).
// blockIdx -> b = idx & 7 so each batch pins to one XCD (round-robin dispatch)
// => k[b] + value[b] (2 MB) stays resident in that XCD's 4 MiB L2.
// ---------------------------------------------------------------------------
__global__ __launch_bounds__(256) void attn_kernel(
    const float* __restrict__ qproj,   // [B*T, D] rows = b*T+t
    const float* __restrict__ kproj,   // [B*S, D]
    const float* __restrict__ value,   // [B, S, D]
    const int*   __restrict__ mask,    // [B, S] (0/1)
    const float* __restrict__ scale,   // [D]
    float*       __restrict__ ctx_out, // [B*T, D]
    float*       __restrict__ attn_out)// [B*T, S]
{
    const int b   = blockIdx.x & 7;    // XCD pin
    const int t   = blockIdx.x >> 3;
    const int row = b * T_ + t;
    const int tid = threadIdx.x;
    const int lane = tid & 63;
    const int wid  = tid >> 6;

    __shared__ float sc_lds[S_];
    __shared__ float red[8];

    // Each lane owns d = lane*8 .. lane*8+7; q and scale live in registers.
    const int d0 = lane * 8;
    const float* qrow = qproj + (size_t)row * D_ + d0;
    float4 q0 = *(const float4*)(qrow);
    float4 q1 = *(const float4*)(qrow + 4);
    float4 c0 = *(const float4*)(scale + d0);
    float4 c1 = *(const float4*)(scale + d0 + 4);

    const float* kbase = kproj + (size_t)b * S_ * D_ + d0;
    const int*   mrow  = mask + b * S_;

    // Phase 1: scores[s] = sum_d scale*tanh(q+k), masked.
    for (int s = wid; s < S_; s += 4) {
        const float* krow = kbase + (size_t)s * D_;
        float4 k0 = *(const float4*)(krow);
        float4 k1 = *(const float4*)(krow + 4);
        float p = 0.f;
        p = fmaf(c0.x, tanh_fast(q0.x + k0.x), p);
        p = fmaf(c0.y, tanh_fast(q0.y + k0.y), p);
        p = fmaf(c0.z, tanh_fast(q0.z + k0.z), p);
        p = fmaf(c0.w, tanh_fast(q0.w + k0.w), p);
        p = fmaf(c1.x, tanh_fast(q1.x + k1.x), p);
        p = fmaf(c1.y, tanh_fast(q1.y + k1.y), p);
        p = fmaf(c1.z, tanh_fast(q1.z + k1.z), p);
        p = fmaf(c1.w, tanh_fast(q1.w + k1.w), p);
        p += __shfl_xor(p, 32);
        p += __shfl_xor(p, 16);
        p += __shfl_xor(p, 8);
        p += __shfl_xor(p, 4);
        p += __shfl_xor(p, 2);
        p += __shfl_xor(p, 1);
        if (lane == 0) sc_lds[s] = mrow[s] ? p : -1e9f;
    }
    __syncthreads();

    // Phase 2: softmax over 512 scores (each thread owns 2).
    float s0v = sc_lds[tid], s1v = sc_lds[tid + 256];
    float m = fmaxf(s0v, s1v);
    m = fmaxf(m, __shfl_xor(m, 32));
    m = fmaxf(m, __shfl_xor(m, 16));
    m = fmaxf(m, __shfl_xor(m, 8));
    m = fmaxf(m, __shfl_xor(m, 4));
    m = fmaxf(m, __shfl_xor(m, 2));
    m = fmaxf(m, __shfl_xor(m, 1));
    if (lane == 0) red[wid] = m;
    __syncthreads();
    m = fmaxf(fmaxf(red[0], red[1]), fmaxf(red[2], red[3]));

    float e0 = __builtin_amdgcn_exp2f((s0v - m) * LOG2E);
    float e1 = __builtin_amdgcn_exp2f((s1v - m) * LOG2E);
    float sum = e0 + e1;
    sum += __shfl_xor(sum, 32);
    sum += __shfl_xor(sum, 16);
    sum += __shfl_xor(sum, 8);
    sum += __shfl_xor(sum, 4);
    sum += __shfl_xor(sum, 2);
    sum += __shfl_xor(sum, 1);
    if (lane == 0) red[4 + wid] = sum;
    __syncthreads();
    float tot = (red[4] + red[5]) + (red[6] + red[7]);
    float inv = 1.0f / tot;
    float w0 = e0 * inv, w1 = e1 * inv;

    // Each thread writes only its own two slots; no race before the sync.
    sc_lds[tid] = w0;
    sc_lds[tid + 256] = w1;
    attn_out[(size_t)row * S_ + tid] = w0;
    attn_out[(size_t)row * S_ + tid + 256] = w1;
    __syncthreads();

    // Phase 3: context[v] = sum_s w[s] * value[b,s,v]; thread owns 2 consecutive v.
    const int v0 = tid * 2;
    const float* vbase = value + (size_t)b * S_ * D_ + v0;
    float ax = 0.f, ay = 0.f;
#pragma unroll 4
    for (int s = 0; s < S_; ++s) {
        float w = sc_lds[s];
        float2 vv = *(const float2*)(vbase + (size_t)s * D_);
        ax = fmaf(w, vv.x, ax);
        ay = fmaf(w, vv.y, ay);
    }
    float2 res; res.x = ax; res.y = ay;
    *(float2*)(ctx_out + (size_t)row * D_ + v0) = res;
}

extern "C" void kernel_launch(void* const* d_in, const int* in_sizes, int n_in,
                              void* d_out, int out_size, void* d_ws, size_t ws_size,
                              hipStream_t stream) {
    const float* query = (const float*)d_in[0];  // [8,64,512]
    const float* value = (const float*)d_in[1];  // [8,512,512]
    const int*   mask  = (const int*)  d_in[2];  // [8,512] bool -> int32
    const float* W1w   = (const float*)d_in[3];  // [512,512]
    const float* W1b   = (const float*)d_in[4];  // [512]
    const float* W2w   = (const float*)d_in[5];  // [512,512]
    const float* W2b   = (const float*)d_in[6];  // [512]
    const float* scale = (const float*)d_in[7];  // [512]

    float* ctx  = (float*)d_out;                 // [8,64,512]
    float* attn = (float*)d_out + (size_t)B_ * T_ * D_;  // [8,64,512]

    float* qproj = (float*)d_ws;                 // [512,512]  = 1 MB
    float* kproj = qproj + (size_t)B_ * T_ * D_; // [4096,512] = 8 MB

    // q = query·W1 + b1   (M=512)
    gemm_bias<<<dim3(D_ / BN, (B_ * T_) / BM), 256, 0, stream>>>(
        query, W1w, W1b, qproj, B_ * T_, D_, D_);
    // k = value·W2 + b2   (M=4096)
    gemm_bias<<<dim3(D_ / BN, (B_ * S_) / BM), 256, 0, stream>>>(
        value, W2w, W2b, kproj, B_ * S_, D_, D_);
    // fused scores/softmax/context, one block per (b,t), XCD-pinned by b
    attn_kernel<<<B_ * T_, 256, 0, stream>>>(
        qproj, kproj, value, mask, scale, ctx, attn);
}

// Round 2
// 190.127 us; speedup vs baseline: 1.3717x; 1.3717x over previous
//
#include <hip/hip_runtime.h>
#include <hip/hip_bf16.h>

// Dims fixed by setup_inputs(): b=8, t=64, s=512, qu=vu=d=512.
#define B_  8
#define T_  64
#define S_  512
#define D_  512

#define QN (512 * 512)      // qproj elements (B*T x D)
#define KN (4096 * 512)     // kproj elements (B*S x D)
#define SN (B_ * T_ * S_)   // scores elements

#define TLOG2E 2.8853900817779268f   // 2*log2(e)
#define LOG2E  1.4426950408889634f

__device__ __forceinline__ float tanh_fast(float x) {
    float e2 = __builtin_amdgcn_exp2f(x * TLOG2E);
    float r  = __builtin_amdgcn_rcpf(e2 + 1.0f);
    return fmaf(-2.0f, r, 1.0f);
}

// ---------------------------------------------------------------------------
// Fused projection GEMMs with optional split-K into partial buffers.
// Block decode:
//   x in [0, 512*ksplit):  k-proj (value @ W2), tiles 64x8, split = x>>9
//   rest:                  q-proj (query @ W1), tiles 8x8,  split = r>>6
// C is written (not accumulated); partials summed by reduce_parts.
// ---------------------------------------------------------------------------
#define BM 64
#define BN 64
#define BK 16

__global__ __launch_bounds__(256) void proj_gemm(
    const float* __restrict__ query, const float* __restrict__ value,
    const float* __restrict__ W1, const float* __restrict__ W2,
    float* __restrict__ qC, float* __restrict__ kC,
    int ksplit, int qsplit)
{
    __shared__ float As[BK][BM + 4];
    __shared__ float Bs[BK][BN + 4];

    const int x = blockIdx.x;
    const int ktb = 512 * ksplit;

    const float* A; const float* Bw; float* C;
    int kbeg, klen, tm, tn;
    if (x < ktb) {
        int split = x >> 9;          // x / 512
        int tile  = x & 511;
        tm = tile >> 3; tn = tile & 7;
        klen = 512 / ksplit; kbeg = split * klen;
        A = value; Bw = W2;
        C = kC + (size_t)split * KN;
    } else {
        int r = x - ktb;
        int split = r >> 6;          // r / 64
        int tile  = r & 63;
        tm = tile >> 3; tn = tile & 7;
        klen = 512 / qsplit; kbeg = split * klen;
        A = query; Bw = W1;
        C = qC + (size_t)split * QN;
    }
    const int kend = kbeg + klen;

    const int tid = threadIdx.x;
    const int tx = tid & 15, ty = tid >> 4;

    float acc[4][4] = {};

    const int a_row = tid >> 2;
    const int a_k4  = (tid & 3) * 4;
    const int b_k   = tid >> 4;
    const int b_c4  = (tid & 15) * 4;

    const float* Ablk = A + (size_t)(tm * BM) * D_;
    const float* Bblk = Bw + tn * BN;

    for (int k0 = kbeg; k0 < kend; k0 += BK) {
        float4 av = *(const float4*)(Ablk + (size_t)a_row * D_ + k0 + a_k4);
        float4 bv = *(const float4*)(Bblk + (size_t)(k0 + b_k) * D_ + b_c4);
        As[a_k4 + 0][a_row] = av.x;
        As[a_k4 + 1][a_row] = av.y;
        As[a_k4 + 2][a_row] = av.z;
        As[a_k4 + 3][a_row] = av.w;
        *(float4*)&Bs[b_k][b_c4] = bv;
        __syncthreads();
#pragma unroll
        for (int kk = 0; kk < BK; ++kk) {
            float4 a = *(const float4*)&As[kk][ty * 4];
            float4 b = *(const float4*)&Bs[kk][tx * 4];
            acc[0][0] = fmaf(a.x, b.x, acc[0][0]);
            acc[0][1] = fmaf(a.x, b.y, acc[0][1]);
            acc[0][2] = fmaf(a.x, b.z, acc[0][2]);
            acc[0][3] = fmaf(a.x, b.w, acc[0][3]);
            acc[1][0] = fmaf(a.y, b.x, acc[1][0]);
            acc[1][1] = fmaf(a.y, b.y, acc[1][1]);
            acc[1][2] = fmaf(a.y, b.z, acc[1][2]);
            acc[1][3] = fmaf(a.y, b.w, acc[1][3]);
            acc[2][0] = fmaf(a.z, b.x, acc[2][0]);
            acc[2][1] = fmaf(a.z, b.y, acc[2][1]);
            acc[2][2] = fmaf(a.z, b.z, acc[2][2]);
            acc[2][3] = fmaf(a.z, b.w, acc[2][3]);
            acc[3][0] = fmaf(a.w, b.x, acc[3][0]);
            acc[3][1] = fmaf(a.w, b.y, acc[3][1]);
            acc[3][2] = fmaf(a.w, b.z, acc[3][2]);
            acc[3][3] = fmaf(a.w, b.w, acc[3][3]);
        }
        __syncthreads();
    }

    const int row0 = tm * BM + ty * 4;
    const int col0 = tn * BN + tx * 4;
#pragma unroll
    for (int i = 0; i < 4; ++i) {
        float4 o;
        o.x = acc[i][0]; o.y = acc[i][1]; o.z = acc[i][2]; o.w = acc[i][3];
        *(float4*)(C + (size_t)(row0 + i) * D_ + col0) = o;
    }
}

// Sum split-K partials: kproj = kpart0+kpart1; qproj = qpart0..3.
__global__ __launch_bounds__(256) void reduce_parts(
    const float* __restrict__ kpart, const float* __restrict__ qpart,
    float* __restrict__ kproj, float* __restrict__ qproj)
{
    int i = (blockIdx.x * 256 + threadIdx.x) * 4;
    if (i < KN) {
        float4 a = *(const float4*)(kpart + i);
        float4 b = *(const float4*)(kpart + KN + i);
        float4 o; o.x = a.x + b.x; o.y = a.y + b.y; o.z = a.z + b.z; o.w = a.w + b.w;
        *(float4*)(kproj + i) = o;
    } else {
        int j = i - KN;
        float4 a = *(const float4*)(qpart + j);
        float4 b = *(const float4*)(qpart + QN + j);
        float4 c = *(const float4*)(qpart + 2 * QN + j);
        float4 d = *(const float4*)(qpart + 3 * QN + j);
        float4 o;
        o.x = (a.x + b.x) + (c.x + d.x);
        o.y = (a.y + b.y) + (c.y + d.y);
        o.z = (a.z + b.z) + (c.z + d.z);
        o.w = (a.w + b.w) + (c.w + d.w);
        *(float4*)(qproj + j) = o;
    }
}

// ---------------------------------------------------------------------------
// Scores: scores[b,t,s] = sum_d scale[d]*tanh(qproj+b1 + kproj+b2), masked.
// Grid = 2048: blk = ((t*4 + sc) << 3) | b  -> b in low bits = XCD pin.
// Block handles one t, s-chunk of 128 (wave w: s = sc*128 + w + 4*i).
// ---------------------------------------------------------------------------
__global__ __launch_bounds__(256) void scores_kernel(
    const float* __restrict__ qproj, const float* __restrict__ kproj,
    const float* __restrict__ b1, const float* __restrict__ b2,
    const int*   __restrict__ mask, const float* __restrict__ scale,
    float* __restrict__ scores)
{
    const int blk = blockIdx.x;
    const int b  = blk & 7;
    const int q  = blk >> 3;
    const int sc = q & 3;
    const int t  = q >> 2;
    const int row = b * T_ + t;

    const int tid = threadIdx.x;
    const int lane = tid & 63;
    const int wid  = tid >> 6;

    const int d0 = lane * 8;
    const float* qrow = qproj + (size_t)row * D_ + d0;
    float4 q0 = *(const float4*)(qrow);
    float4 q1 = *(const float4*)(qrow + 4);
    float4 c0 = *(const float4*)(scale + d0);
    float4 c1 = *(const float4*)(scale + d0 + 4);
    // fold biases: tanh((q+b1)+(k+b2)) = tanh(q_raw+k_raw+(b1+b2))
    float4 b1a = *(const float4*)(b1 + d0);
    float4 b1b = *(const float4*)(b1 + d0 + 4);
    float4 b2a = *(const float4*)(b2 + d0);
    float4 b2b = *(const float4*)(b2 + d0 + 4);
    q0.x += b1a.x + b2a.x; q0.y += b1a.y + b2a.y;
    q0.z += b1a.z + b2a.z; q0.w += b1a.w + b2a.w;
    q1.x += b1b.x + b2b.x; q1.y += b1b.y + b2b.y;
    q1.z += b1b.z + b2b.z; q1.w += b1b.w + b2b.w;

    const float* kbase = kproj + (size_t)b * S_ * D_ + d0;
    const int*   mrow  = mask + b * S_;
    float* srow = scores + (size_t)row * S_;

    const int s_end = sc * 128 + 128;
    for (int s = sc * 128 + wid; s < s_end; s += 4) {
        const float* krow = kbase + (size_t)s * D_;
        float4 k0 = *(const float4*)(krow);
        float4 k1 = *(const float4*)(krow + 4);
        float p = 0.f;
        p = fmaf(c0.x, tanh_fast(q0.x + k0.x), p);
        p = fmaf(c0.y, tanh_fast(q0.y + k0.y), p);
        p = fmaf(c0.z, tanh_fast(q0.z + k0.z), p);
        p = fmaf(c0.w, tanh_fast(q0.w + k0.w), p);
        p = fmaf(c1.x, tanh_fast(q1.x + k1.x), p);
        p = fmaf(c1.y, tanh_fast(q1.y + k1.y), p);
        p = fmaf(c1.z, tanh_fast(q1.z + k1.z), p);
        p = fmaf(c1.w, tanh_fast(q1.w + k1.w), p);
        p += __shfl_xor(p, 32);
        p += __shfl_xor(p, 16);
        p += __shfl_xor(p, 8);
        p += __shfl_xor(p, 4);
        p += __shfl_xor(p, 2);
        p += __shfl_xor(p, 1);
        if (lane == 0) srow[s] = mrow[s] ? p : -1e9f;
    }
}

// ---------------------------------------------------------------------------
// Softmax + context. Grid = 512: blk = ((tp*2 + vc) << 3) | b (XCD pin).
// Block: t-pair (2x value reuse), v-chunk of 256. Both rows' softmax done
// as float2 lanes; weights staged in LDS; context loop 1 float/lane/s.
// ---------------------------------------------------------------------------
__global__ __launch_bounds__(256) void softmax_ctx(
    const float* __restrict__ scores, const float* __restrict__ value,
    float* __restrict__ ctx, float* __restrict__ attn)
{
    const int blk = blockIdx.x;
    const int b  = blk & 7;
    const int r  = blk >> 3;
    const int vc = r & 1;
    const int tp = r >> 1;
    const int t0 = tp * 2, t1 = t0 + 1;
    const size_t row0 = (size_t)(b * T_ + t0) * S_;
    const size_t row1 = (size_t)(b * T_ + t1) * S_;

    const int tid = threadIdx.x;
    const int lane = tid & 63;
    const int wid  = tid >> 6;

    __shared__ float w0s[S_];
    __shared__ float w1s[S_];
    __shared__ float2 red2[8];

    const int sa = tid, sb = tid + 256;
    float2 xa, xb;
    xa.x = scores[row0 + sa]; xa.y = scores[row1 + sa];
    xb.x = scores[row0 + sb]; xb.y = scores[row1 + sb];

    // block max (per row, packed float2)
    float2 m2; m2.x = fmaxf(xa.x, xb.x); m2.y = fmaxf(xa.y, xb.y);
#pragma unroll
    for (int off = 32; off >= 1; off >>= 1) {
        m2.x = fmaxf(m2.x, __shfl_xor(m2.x, off));
        m2.y = fmaxf(m2.y, __shfl_xor(m2.y, off));
    }
    if (lane == 0) red2[wid] = m2;
    __syncthreads();
    {
        float2 r0 = red2[0], r1 = red2[1], r2 = red2[2], r3 = red2[3];
        m2.x = fmaxf(fmaxf(r0.x, r1.x), fmaxf(r2.x, r3.x));
        m2.y = fmaxf(fmaxf(r0.y, r1.y), fmaxf(r2.y, r3.y));
    }

    float2 ea, eb;
    ea.x = __builtin_amdgcn_exp2f((xa.x - m2.x) * LOG2E);
    ea.y = __builtin_amdgcn_exp2f((xa.y - m2.y) * LOG2E);
    eb.x = __builtin_amdgcn_exp2f((xb.x - m2.x) * LOG2E);
    eb.y = __builtin_amdgcn_exp2f((xb.y - m2.y) * LOG2E);

    float2 s2; s2.x = ea.x + eb.x; s2.y = ea.y + eb.y;
#pragma unroll
    for (int off = 32; off >= 1; off >>= 1) {
        s2.x += __shfl_xor(s2.x, off);
        s2.y += __shfl_xor(s2.y, off);
    }
    if (lane == 0) red2[4 + wid] = s2;
    __syncthreads();
    {
        float2 r0 = red2[4], r1 = red2[5], r2 = red2[6], r3 = red2[7];
        s2.x = (r0.x + r1.x) + (r2.x + r3.x);
        s2.y = (r0.y + r1.y) + (r2.y + r3.y);
    }
    const float inv0 = 1.0f / s2.x, inv1 = 1.0f / s2.y;

    float wa0 = ea.x * inv0, wb0 = eb.x * inv0;
    float wa1 = ea.y * inv1, wb1 = eb.y * inv1;

    w0s[sa] = wa0; w0s[sb] = wb0;
    w1s[sa] = wa1; w1s[sb] = wb1;
    if (vc == 0) {
        attn[row0 + sa] = wa0; attn[row0 + sb] = wb0;
        attn[row1 + sa] = wa1; attn[row1 + sb] = wb1;
    }
    __syncthreads();

    // context over v-chunk
    const int v = vc * 256 + tid;
    const float* vbase = value + (size_t)b * S_ * D_ + v;
    float a0 = 0.f, a1 = 0.f;
#pragma unroll 8
    for (int s = 0; s < S_; ++s) {
        float vv = vbase[(size_t)s * D_];
        a0 = fmaf(w0s[s], vv, a0);
        a1 = fmaf(w1s[s], vv, a1);
    }
    ctx[(size_t)(b * T_ + t0) * D_ + v] = a0;
    ctx[(size_t)(b * T_ + t1) * D_ + v] = a1;
}

extern "C" void kernel_launch(void* const* d_in, const int* in_sizes, int n_in,
                              void* d_out, int out_size, void* d_ws, size_t ws_size,
                              hipStream_t stream) {
    const float* query = (const float*)d_in[0];
    const float* value = (const float*)d_in[1];
    const int*   mask  = (const int*)  d_in[2];
    const float* W1w   = (const float*)d_in[3];
    const float* W1b   = (const float*)d_in[4];
    const float* W2w   = (const float*)d_in[5];
    const float* W2b   = (const float*)d_in[6];
    const float* scale = (const float*)d_in[7];

    float* ctx  = (float*)d_out;
    float* attn = (float*)d_out + (size_t)B_ * T_ * D_;

    float* qproj  = (float*)d_ws;
    float* kproj  = qproj + QN;
    float* scbuf  = kproj + KN;
    float* kpart  = scbuf + SN;          // 2*KN
    float* qpart  = kpart + 2 * (size_t)KN;  // 4*QN

    const size_t need = (size_t)(QN + KN + SN + 2 * KN + 4 * QN) * sizeof(float);
    const bool use_split = ws_size >= need;

    if (use_split) {
        // k-GEMM split-K=2 (1024 blocks) + q-GEMM split-K=4 (256 blocks)
        proj_gemm<<<512 * 2 + 64 * 4, 256, 0, stream>>>(
            query, value, W1w, W2w, qpart, kpart, 2, 4);
        reduce_parts<<<(KN + QN) / (256 * 4), 256, 0, stream>>>(
            kpart, qpart, kproj, qproj);
    } else {
        proj_gemm<<<512 + 64, 256, 0, stream>>>(
            query, value, W1w, W2w, qproj, kproj, 1, 1);
    }

    scores_kernel<<<2048, 256, 0, stream>>>(
        qproj, kproj, W1b, W2b, mask, scale, scbuf);

    softmax_ctx<<<512, 256, 0, stream>>>(scbuf, value, ctx, attn);
}

// Round 3
// 165.571 us; speedup vs baseline: 1.5752x; 1.1483x over previous
//
#include <hip/hip_runtime.h>
#include <hip/hip_bf16.h>

// Dims fixed by setup_inputs(): b=8, t=64, s=512, qu=vu=d=512.
#define B_  8
#define T_  64
#define S_  512
#define D_  512

#define QN (512 * 512)      // qproj elements (B*T x D)
#define KN (4096 * 512)     // kproj elements (B*S x D)
#define SN (B_ * T_ * S_)   // scores elements

#define TLOG2E 2.8853900817779268f   // 2*log2(e)
#define LOG2E  1.4426950408889634f

// ---------------------------------------------------------------------------
// Fused projection GEMMs, split-K partials (summed by consumers, NOT here).
// k-GEMM (value@W2): ksplit=2, blocks 0..1023:
//   x = ((split*64 + tm_lo*8 + tn) << 3) | b     (b in low bits = XCD pin)
//   tm = b*8 + tm_lo (8 row-tiles per batch), K-depth 256.
// q-GEMM (query@W1): qsplit=4, blocks 1024..1279:
//   r = x-1024: tm = r&7 (tm==batch), tn = (r>>3)&7, split = r>>6, K-depth 128.
// ---------------------------------------------------------------------------
#define BM 64
#define BN 64
#define BK 32

__global__ __launch_bounds__(256) void proj_gemm(
    const float* __restrict__ query, const float* __restrict__ value,
    const float* __restrict__ W1, const float* __restrict__ W2,
    float* __restrict__ qpart, float* __restrict__ kpart)
{
    __shared__ float As[BK][BM + 4];
    __shared__ float Bs[BK][BN + 4];

    const int x = blockIdx.x;
    const float* A; const float* Bw; float* C;
    int kbeg, klen, tm, tn;
    if (x < 1024) {
        int b = x & 7;
        int r = x >> 3;
        tn = r & 7;
        int tml = (r >> 3) & 7;
        int split = r >> 6;          // 0..1
        tm = b * 8 + tml;
        klen = 256; kbeg = split * 256;
        A = value; Bw = W2;
        C = kpart + (size_t)split * KN;
    } else {
        int r = x - 1024;
        tm = r & 7;
        tn = (r >> 3) & 7;
        int split = r >> 6;          // 0..3
        klen = 128; kbeg = split * 128;
        A = query; Bw = W1;
        C = qpart + (size_t)split * QN;
    }
    const int kend = kbeg + klen;

    const int tid = threadIdx.x;
    const int tx = tid & 15, ty = tid >> 4;

    float acc[4][4] = {};

    const int a_row = tid >> 2;          // 0..63
    const int a_k8  = (tid & 3) * 8;     // 0,8,16,24
    const int b_k   = tid >> 4;          // 0..15
    const int b_c4  = (tid & 15) * 4;

    const float* Ablk = A + (size_t)(tm * BM) * D_;
    const float* Bblk = Bw + tn * BN;

    for (int k0 = kbeg; k0 < kend; k0 += BK) {
        float4 av0 = *(const float4*)(Ablk + (size_t)a_row * D_ + k0 + a_k8);
        float4 av1 = *(const float4*)(Ablk + (size_t)a_row * D_ + k0 + a_k8 + 4);
        float4 bv0 = *(const float4*)(Bblk + (size_t)(k0 + b_k) * D_ + b_c4);
        float4 bv1 = *(const float4*)(Bblk + (size_t)(k0 + b_k + 16) * D_ + b_c4);
        As[a_k8 + 0][a_row] = av0.x;
        As[a_k8 + 1][a_row] = av0.y;
        As[a_k8 + 2][a_row] = av0.z;
        As[a_k8 + 3][a_row] = av0.w;
        As[a_k8 + 4][a_row] = av1.x;
        As[a_k8 + 5][a_row] = av1.y;
        As[a_k8 + 6][a_row] = av1.z;
        As[a_k8 + 7][a_row] = av1.w;
        *(float4*)&Bs[b_k][b_c4] = bv0;
        *(float4*)&Bs[b_k + 16][b_c4] = bv1;
        __syncthreads();
#pragma unroll
        for (int kk = 0; kk < BK; ++kk) {
            float4 a = *(const float4*)&As[kk][ty * 4];
            float4 b = *(const float4*)&Bs[kk][tx * 4];
            acc[0][0] = fmaf(a.x, b.x, acc[0][0]);
            acc[0][1] = fmaf(a.x, b.y, acc[0][1]);
            acc[0][2] = fmaf(a.x, b.z, acc[0][2]);
            acc[0][3] = fmaf(a.x, b.w, acc[0][3]);
            acc[1][0] = fmaf(a.y, b.x, acc[1][0]);
            acc[1][1] = fmaf(a.y, b.y, acc[1][1]);
            acc[1][2] = fmaf(a.y, b.z, acc[1][2]);
            acc[1][3] = fmaf(a.y, b.w, acc[1][3]);
            acc[2][0] = fmaf(a.z, b.x, acc[2][0]);
            acc[2][1] = fmaf(a.z, b.y, acc[2][1]);
            acc[2][2] = fmaf(a.z, b.z, acc[2][2]);
            acc[2][3] = fmaf(a.z, b.w, acc[2][3]);
            acc[3][0] = fmaf(a.w, b.x, acc[3][0]);
            acc[3][1] = fmaf(a.w, b.y, acc[3][1]);
            acc[3][2] = fmaf(a.w, b.z, acc[3][2]);
            acc[3][3] = fmaf(a.w, b.w, acc[3][3]);
        }
        __syncthreads();
    }

    const int row0 = tm * BM + ty * 4;
    const int col0 = tn * BN + tx * 4;
#pragma unroll
    for (int i = 0; i < 4; ++i) {
        float4 o;
        o.x = acc[i][0]; o.y = acc[i][1]; o.z = acc[i][2]; o.w = acc[i][3];
        *(float4*)(C + (size_t)(row0 + i) * D_ + col0) = o;
    }
}

// ---------------------------------------------------------------------------
// Scores: scores[b,t,s] = csum - 2 * sum_d c_d * rcp(exp2((q'+k')) + 1)
// where q' = (Σ qparts + b1 + b2)*2log2e (regs, 4 t's), k' = (Σ kparts)*2log2e.
// Grid 1024: blk = ((tg*8 + sc) << 3) | b. Block: 4 t's, s-chunk of 64.
// ---------------------------------------------------------------------------
__global__ __launch_bounds__(256) void scores_kernel(
    const float* __restrict__ qpart, const float* __restrict__ kpart,
    const float* __restrict__ b1, const float* __restrict__ b2,
    const int*   __restrict__ mask, const float* __restrict__ scale,
    float* __restrict__ scores)
{
    const int blk = blockIdx.x;
    const int b  = blk & 7;
    int r = blk >> 3;
    const int sc = r & 7;        // s-chunk of 64
    const int tg = r >> 3;       // 0..15
    const int t0 = tg * 4;

    const int tid  = threadIdx.x;
    const int lane = tid & 63;
    const int wid  = tid >> 6;
    const int d0   = lane * 8;

    // scale in regs + full-D sum of scale (csum)
    float c[8];
    *(float4*)&c[0] = *(const float4*)(scale + d0);
    *(float4*)&c[4] = *(const float4*)(scale + d0 + 4);
    float cl = ((c[0] + c[1]) + (c[2] + c[3])) + ((c[4] + c[5]) + (c[6] + c[7]));
#pragma unroll
    for (int off = 32; off >= 1; off >>= 1) cl += __shfl_xor(cl, off);
    const float csum = cl;

    // bias fold
    float bias[8];
    {
        float4 a0 = *(const float4*)(b1 + d0);
        float4 a1 = *(const float4*)(b1 + d0 + 4);
        float4 e0 = *(const float4*)(b2 + d0);
        float4 e1 = *(const float4*)(b2 + d0 + 4);
        bias[0] = a0.x + e0.x; bias[1] = a0.y + e0.y;
        bias[2] = a0.z + e0.z; bias[3] = a0.w + e0.w;
        bias[4] = a1.x + e1.x; bias[5] = a1.y + e1.y;
        bias[6] = a1.z + e1.z; bias[7] = a1.w + e1.w;
    }

    // q' for 4 t's: sum of 4 split-K partials + bias, pre-scaled by 2log2e
    float qt[4][8];
#pragma unroll
    for (int t = 0; t < 4; ++t) {
        const float* qp = qpart + (size_t)(b * T_ + t0 + t) * D_ + d0;
        float4 p0a = *(const float4*)(qp);
        float4 p0b = *(const float4*)(qp + 4);
        float4 p1a = *(const float4*)(qp + QN);
        float4 p1b = *(const float4*)(qp + QN + 4);
        float4 p2a = *(const float4*)(qp + 2 * QN);
        float4 p2b = *(const float4*)(qp + 2 * QN + 4);
        float4 p3a = *(const float4*)(qp + 3 * QN);
        float4 p3b = *(const float4*)(qp + 3 * QN + 4);
        qt[t][0] = ((p0a.x + p1a.x) + (p2a.x + p3a.x) + bias[0]) * TLOG2E;
        qt[t][1] = ((p0a.y + p1a.y) + (p2a.y + p3a.y) + bias[1]) * TLOG2E;
        qt[t][2] = ((p0a.z + p1a.z) + (p2a.z + p3a.z) + bias[2]) * TLOG2E;
        qt[t][3] = ((p0a.w + p1a.w) + (p2a.w + p3a.w) + bias[3]) * TLOG2E;
        qt[t][4] = ((p0b.x + p1b.x) + (p2b.x + p3b.x) + bias[4]) * TLOG2E;
        qt[t][5] = ((p0b.y + p1b.y) + (p2b.y + p3b.y) + bias[5]) * TLOG2E;
        qt[t][6] = ((p0b.z + p1b.z) + (p2b.z + p3b.z) + bias[6]) * TLOG2E;
        qt[t][7] = ((p0b.w + p1b.w) + (p2b.w + p3b.w) + bias[7]) * TLOG2E;
    }

    const float* kb = kpart + (size_t)(b * S_) * D_ + d0;
    const int*   mrow = mask + b * S_;
    float* sbase = scores + (size_t)(b * T_ + t0) * S_;

    const int s_end = sc * 64 + 64;
    for (int s = sc * 64 + wid; s < s_end; s += 4) {
        const float* kr = kb + (size_t)s * D_;
        float4 ka0 = *(const float4*)(kr);
        float4 ka1 = *(const float4*)(kr + 4);
        float4 kc0 = *(const float4*)(kr + KN);
        float4 kc1 = *(const float4*)(kr + KN + 4);
        float kk[8];
        kk[0] = (ka0.x + kc0.x) * TLOG2E;
        kk[1] = (ka0.y + kc0.y) * TLOG2E;
        kk[2] = (ka0.z + kc0.z) * TLOG2E;
        kk[3] = (ka0.w + kc0.w) * TLOG2E;
        kk[4] = (ka1.x + kc1.x) * TLOG2E;
        kk[5] = (ka1.y + kc1.y) * TLOG2E;
        kk[6] = (ka1.z + kc1.z) * TLOG2E;
        kk[7] = (ka1.w + kc1.w) * TLOG2E;

        float p0 = 0.f, p1 = 0.f, p2 = 0.f, p3 = 0.f;
#pragma unroll
        for (int j = 0; j < 8; ++j) {
            float e0 = __builtin_amdgcn_exp2f(qt[0][j] + kk[j]);
            float e1 = __builtin_amdgcn_exp2f(qt[1][j] + kk[j]);
            float e2 = __builtin_amdgcn_exp2f(qt[2][j] + kk[j]);
            float e3 = __builtin_amdgcn_exp2f(qt[3][j] + kk[j]);
            float r0 = __builtin_amdgcn_rcpf(e0 + 1.0f);
            float r1 = __builtin_amdgcn_rcpf(e1 + 1.0f);
            float r2 = __builtin_amdgcn_rcpf(e2 + 1.0f);
            float r3 = __builtin_amdgcn_rcpf(e3 + 1.0f);
            p0 = fmaf(c[j], r0, p0);
            p1 = fmaf(c[j], r1, p1);
            p2 = fmaf(c[j], r2, p2);
            p3 = fmaf(c[j], r3, p3);
        }
#pragma unroll
        for (int off = 32; off >= 1; off >>= 1) {
            p0 += __shfl_xor(p0, off);
            p1 += __shfl_xor(p1, off);
            p2 += __shfl_xor(p2, off);
            p3 += __shfl_xor(p3, off);
        }
        if (lane == 0) {
            const bool m = mrow[s] != 0;
            float* sp = sbase + s;
            sp[0]      = m ? fmaf(-2.f, p0, csum) : -1e9f;
            sp[S_]     = m ? fmaf(-2.f, p1, csum) : -1e9f;
            sp[2 * S_] = m ? fmaf(-2.f, p2, csum) : -1e9f;
            sp[3 * S_] = m ? fmaf(-2.f, p3, csum) : -1e9f;
        }
    }
}

// ---------------------------------------------------------------------------
// Softmax + context. Grid 1024: blk = ((tp*4 + vc) << 3) | b.
// Block: t-pair, v-chunk of 128; each wave owns one s-quarter (128 s),
// thread owns 2 consecutive v (float2 loads); LDS combine of 4 partials.
// ---------------------------------------------------------------------------
__global__ __launch_bounds__(256) void softmax_ctx(
    const float* __restrict__ scores, const float* __restrict__ value,
    float* __restrict__ ctx, float* __restrict__ attn)
{
    const int blk = blockIdx.x;
    const int b = blk & 7;
    int r = blk >> 3;
    const int vc = r & 3;        // v-chunk of 128
    const int tp = r >> 2;       // 0..31
    const int t0 = tp * 2, t1 = t0 + 1;
    const size_t row0 = (size_t)(b * T_ + t0) * S_;
    const size_t row1 = row0 + S_;

    const int tid  = threadIdx.x;
    const int lane = tid & 63;
    const int wid  = tid >> 6;

    __shared__ float2 wp[S_];          // (w_t0, w_t1) per s
    __shared__ float2 part[2][4][64];  // [t][s-quarter][v-pair]
    __shared__ float2 red2[8];

    const int sa = tid, sb = tid + 256;
    float2 xa, xb;
    xa.x = scores[row0 + sa]; xa.y = scores[row1 + sa];
    xb.x = scores[row0 + sb]; xb.y = scores[row1 + sb];

    float2 m2; m2.x = fmaxf(xa.x, xb.x); m2.y = fmaxf(xa.y, xb.y);
#pragma unroll
    for (int off = 32; off >= 1; off >>= 1) {
        m2.x = fmaxf(m2.x, __shfl_xor(m2.x, off));
        m2.y = fmaxf(m2.y, __shfl_xor(m2.y, off));
    }
    if (lane == 0) red2[wid] = m2;
    __syncthreads();
    {
        float2 r0 = red2[0], r1 = red2[1], r2 = red2[2], r3 = red2[3];
        m2.x = fmaxf(fmaxf(r0.x, r1.x), fmaxf(r2.x, r3.x));
        m2.y = fmaxf(fmaxf(r0.y, r1.y), fmaxf(r2.y, r3.y));
    }

    float2 ea, eb;
    ea.x = __builtin_amdgcn_exp2f((xa.x - m2.x) * LOG2E);
    ea.y = __builtin_amdgcn_exp2f((xa.y - m2.y) * LOG2E);
    eb.x = __builtin_amdgcn_exp2f((xb.x - m2.x) * LOG2E);
    eb.y = __builtin_amdgcn_exp2f((xb.y - m2.y) * LOG2E);

    float2 s2; s2.x = ea.x + eb.x; s2.y = ea.y + eb.y;
#pragma unroll
    for (int off = 32; off >= 1; off >>= 1) {
        s2.x += __shfl_xor(s2.x, off);
        s2.y += __shfl_xor(s2.y, off);
    }
    if (lane == 0) red2[4 + wid] = s2;
    __syncthreads();
    {
        float2 r0 = red2[4], r1 = red2[5], r2 = red2[6], r3 = red2[7];
        s2.x = (r0.x + r1.x) + (r2.x + r3.x);
        s2.y = (r0.y + r1.y) + (r2.y + r3.y);
    }
    const float inv0 = 1.0f / s2.x, inv1 = 1.0f / s2.y;

    float wa0 = ea.x * inv0, wb0 = eb.x * inv0;   // t0 at s=sa, sb
    float wa1 = ea.y * inv1, wb1 = eb.y * inv1;   // t1

    float2 wsa; wsa.x = wa0; wsa.y = wa1;
    float2 wsb; wsb.x = wb0; wsb.y = wb1;
    wp[sa] = wsa;
    wp[sb] = wsb;
    if (vc == 0) {
        attn[row0 + sa] = wa0; attn[row0 + sb] = wb0;
        attn[row1 + sa] = wa1; attn[row1 + sb] = wb1;
    }
    __syncthreads();

    // context: wave wid owns s in [wid*128, wid*128+128), thread owns 2 v.
    const int vp = lane;                 // 0..63
    const int v  = vc * 128 + vp * 2;
    const float* vb = value + ((size_t)(b * S_) + wid * 128) * D_ + v;
    float2 a0; a0.x = 0.f; a0.y = 0.f;
    float2 a1; a1.x = 0.f; a1.y = 0.f;
#pragma unroll 8
    for (int i = 0; i < 128; ++i) {
        float2 vv = *(const float2*)(vb + (size_t)i * D_);
        float2 w = wp[wid * 128 + i];
        a0.x = fmaf(w.x, vv.x, a0.x);
        a0.y = fmaf(w.x, vv.y, a0.y);
        a1.x = fmaf(w.y, vv.x, a1.x);
        a1.y = fmaf(w.y, vv.y, a1.y);
    }
    part[0][wid][vp] = a0;
    part[1][wid][vp] = a1;
    __syncthreads();
    if (tid < 64) {
        float2 q0 = part[0][0][tid], q1 = part[0][1][tid];
        float2 q2 = part[0][2][tid], q3 = part[0][3][tid];
        float2 o0;
        o0.x = (q0.x + q1.x) + (q2.x + q3.x);
        o0.y = (q0.y + q1.y) + (q2.y + q3.y);
        *(float2*)(ctx + (size_t)(b * T_ + t0) * D_ + vc * 128 + tid * 2) = o0;
        float2 u0 = part[1][0][tid], u1 = part[1][1][tid];
        float2 u2 = part[1][2][tid], u3 = part[1][3][tid];
        float2 o1;
        o1.x = (u0.x + u1.x) + (u2.x + u3.x);
        o1.y = (u0.y + u1.y) + (u2.y + u3.y);
        *(float2*)(ctx + (size_t)(b * T_ + t1) * D_ + vc * 128 + tid * 2) = o1;
    }
}

extern "C" void kernel_launch(void* const* d_in, const int* in_sizes, int n_in,
                              void* d_out, int out_size, void* d_ws, size_t ws_size,
                              hipStream_t stream) {
    const float* query = (const float*)d_in[0];
    const float* value = (const float*)d_in[1];
    const int*   mask  = (const int*)  d_in[2];
    const float* W1w   = (const float*)d_in[3];
    const float* W1b   = (const float*)d_in[4];
    const float* W2w   = (const float*)d_in[5];
    const float* W2b   = (const float*)d_in[6];
    const float* scale = (const float*)d_in[7];

    float* ctx  = (float*)d_out;
    float* attn = (float*)d_out + (size_t)B_ * T_ * D_;

    float* qpart = (float*)d_ws;              // 4 * QN  (4 MB)
    float* kpart = qpart + 4 * (size_t)QN;    // 2 * KN  (16 MB)
    float* scbuf = kpart + 2 * (size_t)KN;    // SN      (1 MB)

    proj_gemm<<<1280, 256, 0, stream>>>(query, value, W1w, W2w, qpart, kpart);
    scores_kernel<<<1024, 256, 0, stream>>>(qpart, kpart, W1b, W2b, mask, scale, scbuf);
    softmax_ctx<<<1024, 256, 0, stream>>>(scbuf, value, ctx, attn);
}